// Round 13
// baseline (185.441 us; speedup 1.0000x reference)
//
#include <hip/hip_runtime.h>

#define EMBED   1024
#define HEADS   16
#define HDIM    64
#define SEQ     2048
#define BATCH   4
#define QKV_LD  3072

typedef __attribute__((ext_vector_type(8))) short short8v;
typedef __attribute__((ext_vector_type(4))) float floatx4;
typedef __attribute__((ext_vector_type(4))) unsigned int uint4v;

// log2(e)/8 : folded into Q so S comes out in base-2 units
#define QSCALE 0.18033688011112042f

__device__ __forceinline__ unsigned short f2bf(float f) {
    unsigned int u = __builtin_bit_cast(unsigned int, f);
    u += 0x7FFFu + ((u >> 16) & 1u);
    return (unsigned short)(u >> 16);
}

__device__ __forceinline__ float fast_exp2(float x) {
    float r;
    asm("v_exp_f32 %0, %1" : "=v"(r) : "v"(x));
    return r;
}
__device__ __forceinline__ unsigned int cvt_pk_bf16(float lo, float hi) {
    unsigned int r;
    asm("v_cvt_pk_bf16_f32 %0, %1, %2" : "=v"(r) : "v"(lo), "v"(hi));
    return r;
}
// async global->LDS, 16B per lane; LDS dest = wave-uniform base + lane*16
__device__ __forceinline__ void gload_lds16(const unsigned short* g, unsigned short* l) {
    __builtin_amdgcn_global_load_lds(
        (const __attribute__((address_space(1))) unsigned int*)g,
        (__attribute__((address_space(3))) unsigned int*)l, 16, 0, 0);
}

// ---------------------------------------------------------------------------
__global__ __launch_bounds__(256) void cast_f32_bf16(const float* __restrict__ in,
                                                     unsigned short* __restrict__ out) {
    int i = blockIdx.x * 256 + threadIdx.x;
    float4 v = ((const float4*)in)[i];
    unsigned short o[4] = { f2bf(v.x), f2bf(v.y), f2bf(v.z), f2bf(v.w) };
    ((uint2*)out)[i] = *(uint2*)o;
}

// ---------------------------------------------------------------------------
__global__ __launch_bounds__(256) void transpose_cast(const float* __restrict__ in,
                                                      unsigned short* __restrict__ out,
                                                      int K, int N) {
    __shared__ float T[64][65];
    const int k0 = blockIdx.y * 64, n0 = blockIdx.x * 64;
    const int t = threadIdx.x;
    #pragma unroll
    for (int i = 0; i < 4; ++i) {
        int s = i * 256 + t;
        int k = s >> 4, c4 = s & 15;
        float4 v = *(const float4*)(in + (size_t)(k0 + k) * N + n0 + c4 * 4);
        T[k][c4*4+0] = v.x; T[k][c4*4+1] = v.y; T[k][c4*4+2] = v.z; T[k][c4*4+3] = v.w;
    }
    __syncthreads();
    const int n = t >> 2, kc = (t & 3) * 16;
    unsigned short tmp[16];
    #pragma unroll
    for (int j = 0; j < 16; ++j) tmp[j] = f2bf(T[kc + j][n]);
    *(short8v*)(out + (size_t)(n0 + n) * K + k0 + kc)     = *(short8v*)&tmp[0];
    *(short8v*)(out + (size_t)(n0 + n) * K + k0 + kc + 8) = *(short8v*)&tmp[8];
}

// ---------------------------------------------------------------------------
// V slice of qkv_b -> vt [bh][d][kv-permuted] (see round-5 comment).
// ---------------------------------------------------------------------------
__global__ __launch_bounds__(256) void vt_kernel(const unsigned short* __restrict__ qkvb,
                                                 unsigned short* __restrict__ vt) {
    const int bh = blockIdx.y, b = bh >> 4, h = bh & 15;
    const int n0 = blockIdx.x * 64;
    const int t = threadIdx.x;
    __shared__ __align__(16) unsigned short T[64][72];
    #pragma unroll
    for (int i = 0; i < 2; ++i) {
        int s = i * 256 + t;
        int n = s >> 3, c = s & 7;
        short8v v = *(const short8v*)(qkvb + (size_t)(b*SEQ + n0 + n) * QKV_LD + 2*EMBED + h*HDIM + c*8);
        *(short8v*)&T[n][c*8] = v;
    }
    __syncthreads();
    #pragma unroll
    for (int i = 0; i < 2; ++i) {
        int s = i * 256 + t;
        int d = s >> 3, cp = s & 7;
        int c = cp ^ (d & 7);
        int base = (c >> 2) * 32 + (c & 3) * 4;
        unsigned short tmp[8];
        #pragma unroll
        for (int j = 0; j < 8; ++j)
            tmp[j] = T[base + ((j >> 2) << 4) + (j & 3)][d];
        *(short8v*)(vt + ((size_t)bh * HDIM + d) * SEQ + n0 + cp*8) = *(short8v*)&tmp[0];
    }
}

// ---------------------------------------------------------------------------
// bf16 MFMA GEMM, 256x128 tile, BK=64, 512 threads / 8 waves (4M x 2N).
// T4 pipeline: 3 LDS K-tile buffers, 2-tile-deep global_load_lds prefetch,
// counted s_waitcnt vmcnt(6), two 16-MFMA phases per iter.  (Round 12: this
// structure took QKV from 75.6 to ~58 us — keep.)
// ---------------------------------------------------------------------------
template<bool OUT_BF16, bool SCALE_Q>
__global__ __launch_bounds__(512) void gemm_bf16(const unsigned short* __restrict__ A,
                                                 const unsigned short* __restrict__ BT,
                                                 const float* __restrict__ bias,
                                                 void* __restrict__ Cout,
                                                 int M, int N, int K) {
    __shared__ __align__(16) unsigned short As[3][256 * 64];   // 96 KB
    __shared__ __align__(16) unsigned short Bs[3][128 * 64];   // 48 KB
    const int tid = threadIdx.x;
    const int lane = tid & 63;
    const int w = tid >> 6;            // 0..7
    const int wm = w >> 1, wn = w & 1; // 4 x 2 wave grid
    const int lq = lane & 15, lg = lane >> 4;
    const int lq7 = lq & 7;

    const int nbx = N >> 7;                     // BN = 128
    const int per = gridDim.x >> 3;
    const int nf = (blockIdx.x & 7) * per + (blockIdx.x >> 3);
    const int bx = nf % nbx, by = nf / nbx;
    const int row0 = by * 256, col0 = bx * 128;

    int arow[4], acol[4], brow[2], bcol[2];
    #pragma unroll
    for (int i = 0; i < 4; ++i) {
        int ch = w*256 + i*64 + lane;
        arow[i] = ch >> 3;
        acol[i] = ((lane & 7) ^ (arow[i] & 7)) * 8;
    }
    #pragma unroll
    for (int i = 0; i < 2; ++i) {
        int ch = w*128 + i*64 + lane;
        brow[i] = ch >> 3;
        bcol[i] = ((lane & 7) ^ (brow[i] & 7)) * 8;
    }

    const int fbA0 = (wm*64 + lq) * 64 + ((0 + lg) ^ lq7) * 8;
    const int fbA1 = (wm*64 + lq) * 64 + ((4 + lg) ^ lq7) * 8;
    const int fbB0 = (wn*64 + lq) * 64 + ((0 + lg) ^ lq7) * 8;
    const int fbB1 = (wn*64 + lq) * 64 + ((4 + lg) ^ lq7) * 8;

    floatx4 acc[4][4];
    #pragma unroll
    for (int i = 0; i < 4; ++i)
        #pragma unroll
        for (int j = 0; j < 4; ++j)
            acc[i][j] = (floatx4){0.f, 0.f, 0.f, 0.f};

#define GSTAGE_H1(KK_, BUF_) do {                                                              \
        gload_lds16(A  + (size_t)(row0 + arow[0]) * K + (KK_) + acol[0], &As[BUF_][(w*256 +   0) * 8]); \
        gload_lds16(A  + (size_t)(row0 + arow[1]) * K + (KK_) + acol[1], &As[BUF_][(w*256 +  64) * 8]); \
        gload_lds16(BT + (size_t)(col0 + brow[0]) * K + (KK_) + bcol[0], &Bs[BUF_][(w*128 +   0) * 8]); \
    } while (0)
#define GSTAGE_H2(KK_, BUF_) do {                                                              \
        gload_lds16(A  + (size_t)(row0 + arow[2]) * K + (KK_) + acol[2], &As[BUF_][(w*256 + 128) * 8]); \
        gload_lds16(A  + (size_t)(row0 + arow[3]) * K + (KK_) + acol[3], &As[BUF_][(w*256 + 192) * 8]); \
        gload_lds16(BT + (size_t)(col0 + brow[1]) * K + (KK_) + bcol[1], &Bs[BUF_][(w*128 +  64) * 8]); \
    } while (0)

    const int NKT = K >> 6;
    GSTAGE_H1(0, 0);  GSTAGE_H2(0, 0);
    GSTAGE_H1(64, 1); GSTAGE_H2(64, 1);

    int cur = 0;
    for (int kt = 0; kt < NKT; ++kt) {
        if (kt == NKT - 1) asm volatile("s_waitcnt vmcnt(0)" ::: "memory");
        else               asm volatile("s_waitcnt vmcnt(6)" ::: "memory");
        __builtin_amdgcn_s_barrier();
        __builtin_amdgcn_sched_barrier(0);

        int sb = cur + 2; if (sb >= 3) sb -= 3;
        const int kk2 = (kt + 2) << 6;
        const bool do_stage = (kt + 2 < NKT);

        {
            short8v af[4], bf[4];
            #pragma unroll
            for (int mi = 0; mi < 4; ++mi) af[mi] = *(const short8v*)(&As[cur][fbA0 + mi*1024]);
            #pragma unroll
            for (int ni = 0; ni < 4; ++ni) bf[ni] = *(const short8v*)(&Bs[cur][fbB0 + ni*1024]);
            if (do_stage) GSTAGE_H1(kk2, sb);
            __builtin_amdgcn_s_setprio(1);
            #pragma unroll
            for (int mi = 0; mi < 4; ++mi)
                #pragma unroll
                for (int ni = 0; ni < 4; ++ni)
                    acc[mi][ni] = __builtin_amdgcn_mfma_f32_16x16x32_bf16(af[mi], bf[ni], acc[mi][ni], 0, 0, 0);
            __builtin_amdgcn_s_setprio(0);
        }
        __builtin_amdgcn_s_barrier();
        {
            short8v af[4], bf[4];
            #pragma unroll
            for (int mi = 0; mi < 4; ++mi) af[mi] = *(const short8v*)(&As[cur][fbA1 + mi*1024]);
            #pragma unroll
            for (int ni = 0; ni < 4; ++ni) bf[ni] = *(const short8v*)(&Bs[cur][fbB1 + ni*1024]);
            if (do_stage) GSTAGE_H2(kk2, sb);
            __builtin_amdgcn_s_setprio(1);
            #pragma unroll
            for (int mi = 0; mi < 4; ++mi)
                #pragma unroll
                for (int ni = 0; ni < 4; ++ni)
                    acc[mi][ni] = __builtin_amdgcn_mfma_f32_16x16x32_bf16(af[mi], bf[ni], acc[mi][ni], 0, 0, 0);
            __builtin_amdgcn_s_setprio(0);
        }

        cur = (cur == 2) ? 0 : cur + 1;
    }
#undef GSTAGE_H1
#undef GSTAGE_H2

    #pragma unroll
    for (int mi = 0; mi < 4; ++mi) {
        #pragma unroll
        for (int ni = 0; ni < 4; ++ni) {
            int col = col0 + wn*64 + ni*16 + lq;
            float bv = bias[col];
            #pragma unroll
            for (int r = 0; r < 4; ++r) {
                int row = row0 + wm*64 + mi*16 + lg*4 + r;
                float v = acc[mi][ni][r] + bv;
                if constexpr (SCALE_Q) { if (col < EMBED) v *= QSCALE; }
                if constexpr (OUT_BF16)
                    ((unsigned short*)Cout)[(size_t)row * N + col] = f2bf(v);
                else
                    ((float*)Cout)[(size_t)row * N + col] = v;
            }
        }
    }
}

// ---------------------------------------------------------------------------
// MFMA flash attention: QBLK=128, 8 waves / 512 threads (16 q-rows/wave),
// grid 1024 = 4 blocks/CU (round 12: grid 512 = 2/CU capped occupancy at 36%
// and phase-locked MFMA/VALU at 42%/42%).  Swapped QK^T, pi-permuted PV,
// no-max softmax, ones-MFMA lsum, 2-buffer K/V (32 KB), gload_lds staging,
// raw s_barrier, XCD remap.  Per-wave state ~50 VGPR -> 8 waves/SIMD.
// ---------------------------------------------------------------------------
__global__ __launch_bounds__(512) void attn_mfma(const unsigned short* __restrict__ qkvb,
                                                 const unsigned short* __restrict__ vt,
                                                 unsigned short* __restrict__ attout) {
    // XCD remap: flat%8 picks XCD; each XCD gets 8 whole bh (16 q-blocks each)
    const int flat = blockIdx.x;          // 0..1023
    const int idx = flat >> 3;            // 0..127
    const int bh = (flat & 7) * 8 + (idx >> 4);
    const int qb = idx & 15;              // 0..15
    const int b = bh >> 4, h = bh & 15;
    const int tid = threadIdx.x;
    const int lane = tid & 63;
    const int w = tid >> 6;               // 0..7
    const int lq = lane & 15, lg = lane >> 4;
    const int rb = lq & 7;

    __shared__ __align__(16) unsigned short Ks[2][64 * 64];
    __shared__ __align__(16) unsigned short Vs[2][64 * 64];

    // Q fragments: wave w owns 16 q-rows (qb*128 + w*16 ..)
    short8v qf[2];
    const unsigned short* qbase = qkvb + (size_t)(b*SEQ + qb*128 + w*16) * QKV_LD + h*HDIM;
    #pragma unroll
    for (int ks = 0; ks < 2; ++ks)
        qf[ks] = *(const short8v*)(qbase + (size_t)lq * QKV_LD + ks*32 + lg*8);

    floatx4 o[4];
    #pragma unroll
    for (int dt = 0; dt < 4; ++dt)
        o[dt] = (floatx4){0.f, 0.f, 0.f, 0.f};
    floatx4 lacc = (floatx4){0.f, 0.f, 0.f, 0.f};

    const uint4v onesu = (uint4v){0x3F803F80u, 0x3F803F80u, 0x3F803F80u, 0x3F803F80u};
    const short8v onesf = __builtin_bit_cast(short8v, onesu);

    const unsigned short* kbase = qkvb + (size_t)(b*SEQ) * QKV_LD + EMBED + h*HDIM;
    const unsigned short* vbase = vt + (size_t)bh * HDIM * SEQ;

    const int r0 = tid >> 3;
    const int ck0 = (tid & 7) ^ (r0 & 7);
    const int cv0 = tid & 7;

    const int cA = (lg ^ rb) * 8, cB = ((lg ^ rb) ^ 4) * 8;
    const int fbA = lq * 64 + cA, fbB = lq * 64 + cB;

#define STAGE(T_, BUF_) do {                                                       \
        const unsigned short* kb_ = kbase + (size_t)(T_) * 64 * QKV_LD;            \
        const unsigned short* vb_ = vbase + (T_) * 64;                             \
        gload_lds16(kb_ + (size_t)r0 * QKV_LD + ck0*8, &Ks[BUF_][w*512]);          \
        gload_lds16(vb_ + (size_t)r0 * SEQ + cv0*8,    &Vs[BUF_][w*512]);          \
    } while (0)

    const int NT = SEQ / 64;
    STAGE(0, 0);

    for (int kt = 0; kt < NT; ++kt) {
        const int cur = kt & 1;
        asm volatile("s_waitcnt vmcnt(0)" ::: "memory");
        __builtin_amdgcn_s_barrier();
        __builtin_amdgcn_sched_barrier(0);

        if (kt + 1 < NT) STAGE(kt + 1, cur ^ 1);

        const unsigned short* K0 = &Ks[cur][fbA];
        const unsigned short* K1 = &Ks[cur][fbB];
        const unsigned short* V0 = &Vs[cur][fbA];
        const unsigned short* V1 = &Vs[cur][fbB];

        // ---- S^T = K @ Q^T : sacc[n][r] = S[k = n*16+lg*4+r][q = lq]
        floatx4 sacc[4];
        #pragma unroll
        for (int n = 0; n < 4; ++n) {
            short8v kf0 = *(const short8v*)(K0 + n * 1024);
            short8v kf1 = *(const short8v*)(K1 + n * 1024);
            __builtin_amdgcn_s_setprio(1);
            floatx4 z = (floatx4){0.f, 0.f, 0.f, 0.f};
            z = __builtin_amdgcn_mfma_f32_16x16x32_bf16(kf0, qf[0], z, 0, 0, 0);
            sacc[n] = __builtin_amdgcn_mfma_f32_16x16x32_bf16(kf1, qf[1], z, 0, 0, 0);
            __builtin_amdgcn_s_setprio(0);
        }

        // ---- P = exp2(S) (bounded S; no max subtraction) ----
        uint4v afu[2];
        {
            unsigned int pk[4][2];
            #pragma unroll
            for (int n = 0; n < 4; ++n) {
                float p0 = fast_exp2(sacc[n][0]);
                float p1 = fast_exp2(sacc[n][1]);
                float p2 = fast_exp2(sacc[n][2]);
                float p3 = fast_exp2(sacc[n][3]);
                pk[n][0] = cvt_pk_bf16(p0, p1);
                pk[n][1] = cvt_pk_bf16(p2, p3);
            }
            afu[0] = (uint4v){ pk[0][0], pk[0][1], pk[1][0], pk[1][1] };
            afu[1] = (uint4v){ pk[2][0], pk[2][1], pk[3][0], pk[3][1] };
        }

        // ---- lsum += P @ ones;  O += P @ V ----
        __builtin_amdgcn_s_setprio(1);
        lacc = __builtin_amdgcn_mfma_f32_16x16x32_bf16(
            __builtin_bit_cast(short8v, afu[0]), onesf, lacc, 0, 0, 0);
        lacc = __builtin_amdgcn_mfma_f32_16x16x32_bf16(
            __builtin_bit_cast(short8v, afu[1]), onesf, lacc, 0, 0, 0);
        __builtin_amdgcn_s_setprio(0);
        #pragma unroll
        for (int dt = 0; dt < 4; ++dt) {
            short8v vf0 = *(const short8v*)(V0 + dt * 1024);
            short8v vf1 = *(const short8v*)(V1 + dt * 1024);
            __builtin_amdgcn_s_setprio(1);
            o[dt] = __builtin_amdgcn_mfma_f32_16x16x32_bf16(
                __builtin_bit_cast(short8v, afu[0]), vf0, o[dt], 0, 0, 0);
            o[dt] = __builtin_amdgcn_mfma_f32_16x16x32_bf16(
                __builtin_bit_cast(short8v, afu[1]), vf1, o[dt], 0, 0, 0);
            __builtin_amdgcn_s_setprio(0);
        }
    }
#undef STAGE

    // ---- epilogue: lacc rows (lg*4+r) match o rows exactly — no shuffles ----
    #pragma unroll
    for (int dt = 0; dt < 4; ++dt) {
        #pragma unroll
        for (int r = 0; r < 4; ++r) {
            float v = o[dt][r] / lacc[r];
            int row = qb*128 + w*16 + lg*4 + r;
            int col = h*HDIM + dt*16 + lq;
            attout[(size_t)(b*SEQ + row) * EMBED + col] = f2bf(v);
        }
    }
}

// ---------------------------------------------------------------------------
extern "C" void kernel_launch(void* const* d_in, const int* in_sizes, int n_in,
                              void* d_out, int out_size, void* d_ws, size_t ws_size,
                              hipStream_t stream) {
    const float* x      = (const float*)d_in[0];
    const float* W_qkv  = (const float*)d_in[1];
    const float* b_qkv  = (const float*)d_in[2];
    const float* W_proj = (const float*)d_in[3];
    const float* b_proj = (const float*)d_in[4];
    float* out = (float*)d_out;

    const int M = BATCH * SEQ;   // 8192

    char* ws = (char*)d_ws;
    unsigned short* x_b    = (unsigned short*)(ws);                 // 16 MB
    unsigned short* wqkvT  = (unsigned short*)(ws + 16777216);      // 6 MB
    unsigned short* wprojT = (unsigned short*)(ws + 23068672);      // 2 MB
    unsigned short* qkv_b  = (unsigned short*)(ws + 25165824);      // 48 MB
    unsigned short* vt_b   = (unsigned short*)(ws + 75497472);      // 16 MB
    unsigned short* att_b  = (unsigned short*)(ws + 92274688);      // 16 MB

    cast_f32_bf16<<<dim3((M * EMBED) / 1024), 256, 0, stream>>>(x, x_b);
    transpose_cast<<<dim3(QKV_LD / 64, EMBED / 64), 256, 0, stream>>>(W_qkv, wqkvT, EMBED, QKV_LD);
    transpose_cast<<<dim3(EMBED / 64, EMBED / 64), 256, 0, stream>>>(W_proj, wprojT, EMBED, EMBED);

    // QKV: grid (8192/256)*(3072/128) = 32*24 = 768 blocks
    gemm_bf16<true, true><<<dim3(768), 512, 0, stream>>>(
        x_b, wqkvT, b_qkv, qkv_b, M, QKV_LD, EMBED);

    vt_kernel<<<dim3(SEQ / 64, BATCH * HEADS), 256, 0, stream>>>(qkv_b, vt_b);

    // attn: grid 1024 = 4 blocks/CU (QBLK=128)
    attn_mfma<<<dim3(1024), dim3(512), 0, stream>>>(qkv_b, vt_b, att_b);

    // proj: grid (8192/256)*(1024/128) = 32*8 = 256 blocks
    gemm_bf16<false, false><<<dim3(256), 512, 0, stream>>>(
        att_b, wprojT, b_proj, out, M, EMBED, EMBED);
}

// Round 14
// 174.290 us; speedup vs baseline: 1.0640x; 1.0640x over previous
//
#include <hip/hip_runtime.h>

#define EMBED   1024
#define HEADS   16
#define HDIM    64
#define SEQ     2048
#define BATCH   4
#define QKV_LD  3072

typedef __attribute__((ext_vector_type(8))) short short8v;
typedef __attribute__((ext_vector_type(4))) float floatx4;
typedef __attribute__((ext_vector_type(4))) unsigned int uint4v;

// log2(e)/8 : folded into Q so S comes out in base-2 units
#define QSCALE 0.18033688011112042f

__device__ __forceinline__ unsigned short f2bf(float f) {
    unsigned int u = __builtin_bit_cast(unsigned int, f);
    u += 0x7FFFu + ((u >> 16) & 1u);
    return (unsigned short)(u >> 16);
}

__device__ __forceinline__ float fast_exp2(float x) {
    float r;
    asm("v_exp_f32 %0, %1" : "=v"(r) : "v"(x));
    return r;
}
__device__ __forceinline__ unsigned int cvt_pk_bf16(float lo, float hi) {
    unsigned int r;
    asm("v_cvt_pk_bf16_f32 %0, %1, %2" : "=v"(r) : "v"(lo), "v"(hi));
    return r;
}
// async global->LDS, 16B per lane; LDS dest = wave-uniform base + lane*16
__device__ __forceinline__ void gload_lds16(const unsigned short* g, unsigned short* l) {
    __builtin_amdgcn_global_load_lds(
        (const __attribute__((address_space(1))) unsigned int*)g,
        (__attribute__((address_space(3))) unsigned int*)l, 16, 0, 0);
}

// ---------------------------------------------------------------------------
__global__ __launch_bounds__(256) void cast_f32_bf16(const float* __restrict__ in,
                                                     unsigned short* __restrict__ out) {
    int i = blockIdx.x * 256 + threadIdx.x;
    float4 v = ((const float4*)in)[i];
    unsigned short o[4] = { f2bf(v.x), f2bf(v.y), f2bf(v.z), f2bf(v.w) };
    ((uint2*)out)[i] = *(uint2*)o;
}

// ---------------------------------------------------------------------------
__global__ __launch_bounds__(256) void transpose_cast(const float* __restrict__ in,
                                                      unsigned short* __restrict__ out,
                                                      int K, int N) {
    __shared__ float T[64][65];
    const int k0 = blockIdx.y * 64, n0 = blockIdx.x * 64;
    const int t = threadIdx.x;
    #pragma unroll
    for (int i = 0; i < 4; ++i) {
        int s = i * 256 + t;
        int k = s >> 4, c4 = s & 15;
        float4 v = *(const float4*)(in + (size_t)(k0 + k) * N + n0 + c4 * 4);
        T[k][c4*4+0] = v.x; T[k][c4*4+1] = v.y; T[k][c4*4+2] = v.z; T[k][c4*4+3] = v.w;
    }
    __syncthreads();
    const int n = t >> 2, kc = (t & 3) * 16;
    unsigned short tmp[16];
    #pragma unroll
    for (int j = 0; j < 16; ++j) tmp[j] = f2bf(T[kc + j][n]);
    *(short8v*)(out + (size_t)(n0 + n) * K + k0 + kc)     = *(short8v*)&tmp[0];
    *(short8v*)(out + (size_t)(n0 + n) * K + k0 + kc + 8) = *(short8v*)&tmp[8];
}

// ---------------------------------------------------------------------------
// V slice of qkv_b -> vt [bh][d][kv-permuted] (see round-5 comment).
// ---------------------------------------------------------------------------
__global__ __launch_bounds__(256) void vt_kernel(const unsigned short* __restrict__ qkvb,
                                                 unsigned short* __restrict__ vt) {
    const int bh = blockIdx.y, b = bh >> 4, h = bh & 15;
    const int n0 = blockIdx.x * 64;
    const int t = threadIdx.x;
    __shared__ __align__(16) unsigned short T[64][72];
    #pragma unroll
    for (int i = 0; i < 2; ++i) {
        int s = i * 256 + t;
        int n = s >> 3, c = s & 7;
        short8v v = *(const short8v*)(qkvb + (size_t)(b*SEQ + n0 + n) * QKV_LD + 2*EMBED + h*HDIM + c*8);
        *(short8v*)&T[n][c*8] = v;
    }
    __syncthreads();
    #pragma unroll
    for (int i = 0; i < 2; ++i) {
        int s = i * 256 + t;
        int d = s >> 3, cp = s & 7;
        int c = cp ^ (d & 7);
        int base = (c >> 2) * 32 + (c & 3) * 4;
        unsigned short tmp[8];
        #pragma unroll
        for (int j = 0; j < 8; ++j)
            tmp[j] = T[base + ((j >> 2) << 4) + (j & 3)][d];
        *(short8v*)(vt + ((size_t)bh * HDIM + d) * SEQ + n0 + cp*8) = *(short8v*)&tmp[0];
    }
}

// ---------------------------------------------------------------------------
// bf16 MFMA GEMM, 256x128 tile, BK=64, 512 threads / 8 waves (4M x 2N).
// T4 pipeline: 3 LDS K-tile buffers, 2-tile-deep global_load_lds prefetch,
// counted s_waitcnt vmcnt(6), two 16-MFMA phases per iter.  (Round 12 win.)
// ---------------------------------------------------------------------------
template<bool OUT_BF16, bool SCALE_Q>
__global__ __launch_bounds__(512) void gemm_bf16(const unsigned short* __restrict__ A,
                                                 const unsigned short* __restrict__ BT,
                                                 const float* __restrict__ bias,
                                                 void* __restrict__ Cout,
                                                 int M, int N, int K) {
    __shared__ __align__(16) unsigned short As[3][256 * 64];   // 96 KB
    __shared__ __align__(16) unsigned short Bs[3][128 * 64];   // 48 KB
    const int tid = threadIdx.x;
    const int lane = tid & 63;
    const int w = tid >> 6;            // 0..7
    const int wm = w >> 1, wn = w & 1; // 4 x 2 wave grid
    const int lq = lane & 15, lg = lane >> 4;
    const int lq7 = lq & 7;

    const int nbx = N >> 7;                     // BN = 128
    const int per = gridDim.x >> 3;
    const int nf = (blockIdx.x & 7) * per + (blockIdx.x >> 3);
    const int bx = nf % nbx, by = nf / nbx;
    const int row0 = by * 256, col0 = bx * 128;

    int arow[4], acol[4], brow[2], bcol[2];
    #pragma unroll
    for (int i = 0; i < 4; ++i) {
        int ch = w*256 + i*64 + lane;
        arow[i] = ch >> 3;
        acol[i] = ((lane & 7) ^ (arow[i] & 7)) * 8;
    }
    #pragma unroll
    for (int i = 0; i < 2; ++i) {
        int ch = w*128 + i*64 + lane;
        brow[i] = ch >> 3;
        bcol[i] = ((lane & 7) ^ (brow[i] & 7)) * 8;
    }

    const int fbA0 = (wm*64 + lq) * 64 + ((0 + lg) ^ lq7) * 8;
    const int fbA1 = (wm*64 + lq) * 64 + ((4 + lg) ^ lq7) * 8;
    const int fbB0 = (wn*64 + lq) * 64 + ((0 + lg) ^ lq7) * 8;
    const int fbB1 = (wn*64 + lq) * 64 + ((4 + lg) ^ lq7) * 8;

    floatx4 acc[4][4];
    #pragma unroll
    for (int i = 0; i < 4; ++i)
        #pragma unroll
        for (int j = 0; j < 4; ++j)
            acc[i][j] = (floatx4){0.f, 0.f, 0.f, 0.f};

#define GSTAGE_H1(KK_, BUF_) do {                                                              \
        gload_lds16(A  + (size_t)(row0 + arow[0]) * K + (KK_) + acol[0], &As[BUF_][(w*256 +   0) * 8]); \
        gload_lds16(A  + (size_t)(row0 + arow[1]) * K + (KK_) + acol[1], &As[BUF_][(w*256 +  64) * 8]); \
        gload_lds16(BT + (size_t)(col0 + brow[0]) * K + (KK_) + bcol[0], &Bs[BUF_][(w*128 +   0) * 8]); \
    } while (0)
#define GSTAGE_H2(KK_, BUF_) do {                                                              \
        gload_lds16(A  + (size_t)(row0 + arow[2]) * K + (KK_) + acol[2], &As[BUF_][(w*256 + 128) * 8]); \
        gload_lds16(A  + (size_t)(row0 + arow[3]) * K + (KK_) + acol[3], &As[BUF_][(w*256 + 192) * 8]); \
        gload_lds16(BT + (size_t)(col0 + brow[1]) * K + (KK_) + bcol[1], &Bs[BUF_][(w*128 +  64) * 8]); \
    } while (0)

    const int NKT = K >> 6;
    GSTAGE_H1(0, 0);  GSTAGE_H2(0, 0);
    GSTAGE_H1(64, 1); GSTAGE_H2(64, 1);

    int cur = 0;
    for (int kt = 0; kt < NKT; ++kt) {
        if (kt == NKT - 1) asm volatile("s_waitcnt vmcnt(0)" ::: "memory");
        else               asm volatile("s_waitcnt vmcnt(6)" ::: "memory");
        __builtin_amdgcn_s_barrier();
        __builtin_amdgcn_sched_barrier(0);

        int sb = cur + 2; if (sb >= 3) sb -= 3;
        const int kk2 = (kt + 2) << 6;
        const bool do_stage = (kt + 2 < NKT);

        {
            short8v af[4], bf[4];
            #pragma unroll
            for (int mi = 0; mi < 4; ++mi) af[mi] = *(const short8v*)(&As[cur][fbA0 + mi*1024]);
            #pragma unroll
            for (int ni = 0; ni < 4; ++ni) bf[ni] = *(const short8v*)(&Bs[cur][fbB0 + ni*1024]);
            if (do_stage) GSTAGE_H1(kk2, sb);
            __builtin_amdgcn_s_setprio(1);
            #pragma unroll
            for (int mi = 0; mi < 4; ++mi)
                #pragma unroll
                for (int ni = 0; ni < 4; ++ni)
                    acc[mi][ni] = __builtin_amdgcn_mfma_f32_16x16x32_bf16(af[mi], bf[ni], acc[mi][ni], 0, 0, 0);
            __builtin_amdgcn_s_setprio(0);
        }
        __builtin_amdgcn_s_barrier();
        {
            short8v af[4], bf[4];
            #pragma unroll
            for (int mi = 0; mi < 4; ++mi) af[mi] = *(const short8v*)(&As[cur][fbA1 + mi*1024]);
            #pragma unroll
            for (int ni = 0; ni < 4; ++ni) bf[ni] = *(const short8v*)(&Bs[cur][fbB1 + ni*1024]);
            if (do_stage) GSTAGE_H2(kk2, sb);
            __builtin_amdgcn_s_setprio(1);
            #pragma unroll
            for (int mi = 0; mi < 4; ++mi)
                #pragma unroll
                for (int ni = 0; ni < 4; ++ni)
                    acc[mi][ni] = __builtin_amdgcn_mfma_f32_16x16x32_bf16(af[mi], bf[ni], acc[mi][ni], 0, 0, 0);
            __builtin_amdgcn_s_setprio(0);
        }

        cur = (cur == 2) ? 0 : cur + 1;
    }
#undef GSTAGE_H1
#undef GSTAGE_H2

    #pragma unroll
    for (int mi = 0; mi < 4; ++mi) {
        #pragma unroll
        for (int ni = 0; ni < 4; ++ni) {
            int col = col0 + wn*64 + ni*16 + lq;
            float bv = bias[col];
            #pragma unroll
            for (int r = 0; r < 4; ++r) {
                int row = row0 + wm*64 + mi*16 + lg*4 + r;
                float v = acc[mi][ni][r] + bv;
                if constexpr (SCALE_Q) { if (col < EMBED) v *= QSCALE; }
                if constexpr (OUT_BF16)
                    ((unsigned short*)Cout)[(size_t)row * N + col] = f2bf(v);
                else
                    ((float*)Cout)[(size_t)row * N + col] = v;
            }
        }
    }
}

// ---------------------------------------------------------------------------
// MFMA flash attention: 8 waves / 512 threads, QBLK=256 (round-12 shape:
// 36 MFMA/tile/wave — round 13's QBLK=128 regressed), swapped QK^T,
// pi-permuted PV, no-max softmax, ones-MFMA lsum, XCD remap.
// NEW (T4): 3-buffer K/V (48 KB), 2-tile-deep prefetch, counted
// s_waitcnt vmcnt(2) — tile kt's 2 loads are the oldest outstanding; tile
// kt+1's stay in flight.  Never vmcnt(0) except the last iteration.
// ---------------------------------------------------------------------------
__global__ __launch_bounds__(512) void attn_mfma(const unsigned short* __restrict__ qkvb,
                                                 const unsigned short* __restrict__ vt,
                                                 unsigned short* __restrict__ attout) {
    const int flat = blockIdx.x;          // 0..511
    const int idx = flat >> 3;            // 0..63
    const int bh = (flat & 7) * 8 + (idx >> 3);
    const int qb = idx & 7;
    const int b = bh >> 4, h = bh & 15;
    const int tid = threadIdx.x;
    const int lane = tid & 63;
    const int w = tid >> 6;               // 0..7
    const int lq = lane & 15, lg = lane >> 4;
    const int rb = lq & 7;

    __shared__ __align__(16) unsigned short Ks[3][64 * 64];
    __shared__ __align__(16) unsigned short Vs[3][64 * 64];

    short8v qf[2][2];
    const unsigned short* qbase = qkvb + (size_t)(b*SEQ + qb*256 + w*32) * QKV_LD + h*HDIM;
    #pragma unroll
    for (int m = 0; m < 2; ++m)
        #pragma unroll
        for (int ks = 0; ks < 2; ++ks)
            qf[m][ks] = *(const short8v*)(qbase + (size_t)(m*16 + lq) * QKV_LD + ks*32 + lg*8);

    floatx4 o[2][4];
    #pragma unroll
    for (int m = 0; m < 2; ++m)
        #pragma unroll
        for (int dt = 0; dt < 4; ++dt)
            o[m][dt] = (floatx4){0.f, 0.f, 0.f, 0.f};
    floatx4 lacc[2];
    lacc[0] = (floatx4){0.f, 0.f, 0.f, 0.f};
    lacc[1] = (floatx4){0.f, 0.f, 0.f, 0.f};

    const uint4v onesu = (uint4v){0x3F803F80u, 0x3F803F80u, 0x3F803F80u, 0x3F803F80u};
    const short8v onesf = __builtin_bit_cast(short8v, onesu);

    const unsigned short* kbase = qkvb + (size_t)(b*SEQ) * QKV_LD + EMBED + h*HDIM;
    const unsigned short* vbase = vt + (size_t)bh * HDIM * SEQ;

    const int r0 = tid >> 3;
    const int ck0 = (tid & 7) ^ (r0 & 7);
    const int cv0 = tid & 7;

    const int cA = (lg ^ rb) * 8, cB = ((lg ^ rb) ^ 4) * 8;
    const int fbA = lq * 64 + cA, fbB = lq * 64 + cB;

#define STAGE(T_, BUF_) do {                                                       \
        const unsigned short* kb_ = kbase + (size_t)(T_) * 64 * QKV_LD;            \
        const unsigned short* vb_ = vbase + (T_) * 64;                             \
        gload_lds16(kb_ + (size_t)r0 * QKV_LD + ck0*8, &Ks[BUF_][w*512]);          \
        gload_lds16(vb_ + (size_t)r0 * SEQ + cv0*8,    &Vs[BUF_][w*512]);          \
    } while (0)

    const int NT = SEQ / 64;
    STAGE(0, 0);
    STAGE(1, 1);

    int cur = 0;
    for (int kt = 0; kt < NT; ++kt) {
        // counted wait: tile kt's 2 loads are the oldest outstanding
        if (kt == NT - 1) asm volatile("s_waitcnt vmcnt(0)" ::: "memory");
        else              asm volatile("s_waitcnt vmcnt(2)" ::: "memory");
        __builtin_amdgcn_s_barrier();
        __builtin_amdgcn_sched_barrier(0);

        if (kt + 2 < NT) {
            int sb = cur + 2; if (sb >= 3) sb -= 3;
            STAGE(kt + 2, sb);
        }

        const unsigned short* K0 = &Ks[cur][fbA];
        const unsigned short* K1 = &Ks[cur][fbB];
        const unsigned short* V0 = &Vs[cur][fbA];
        const unsigned short* V1 = &Vs[cur][fbB];

        // ---- S^T = K @ Q^T : sacc[m][n][r] = S[k = n*16+lg*4+r][q = m*16+lq]
        floatx4 sacc[2][4];
        #pragma unroll
        for (int n = 0; n < 4; ++n) {
            short8v kf0 = *(const short8v*)(K0 + n * 1024);
            short8v kf1 = *(const short8v*)(K1 + n * 1024);
            __builtin_amdgcn_s_setprio(1);
            #pragma unroll
            for (int m = 0; m < 2; ++m) {
                floatx4 z = (floatx4){0.f, 0.f, 0.f, 0.f};
                z = __builtin_amdgcn_mfma_f32_16x16x32_bf16(kf0, qf[m][0], z, 0, 0, 0);
                sacc[m][n] = __builtin_amdgcn_mfma_f32_16x16x32_bf16(kf1, qf[m][1], z, 0, 0, 0);
            }
            __builtin_amdgcn_s_setprio(0);
        }

        // ---- P = exp2(S) (bounded S; no max subtraction) ----
        uint4v afu[2][2];
        #pragma unroll
        for (int m = 0; m < 2; ++m) {
            unsigned int pk[4][2];
            #pragma unroll
            for (int n = 0; n < 4; ++n) {
                float p0 = fast_exp2(sacc[m][n][0]);
                float p1 = fast_exp2(sacc[m][n][1]);
                float p2 = fast_exp2(sacc[m][n][2]);
                float p3 = fast_exp2(sacc[m][n][3]);
                pk[n][0] = cvt_pk_bf16(p0, p1);
                pk[n][1] = cvt_pk_bf16(p2, p3);
            }
            afu[m][0] = (uint4v){ pk[0][0], pk[0][1], pk[1][0], pk[1][1] };
            afu[m][1] = (uint4v){ pk[2][0], pk[2][1], pk[3][0], pk[3][1] };
        }

        // ---- lsum += P @ ones;  O += P @ V ----
        __builtin_amdgcn_s_setprio(1);
        #pragma unroll
        for (int m = 0; m < 2; ++m) {
            lacc[m] = __builtin_amdgcn_mfma_f32_16x16x32_bf16(
                __builtin_bit_cast(short8v, afu[m][0]), onesf, lacc[m], 0, 0, 0);
            lacc[m] = __builtin_amdgcn_mfma_f32_16x16x32_bf16(
                __builtin_bit_cast(short8v, afu[m][1]), onesf, lacc[m], 0, 0, 0);
        }
        __builtin_amdgcn_s_setprio(0);
        #pragma unroll
        for (int dt = 0; dt < 4; ++dt) {
            short8v vf0 = *(const short8v*)(V0 + dt * 1024);
            short8v vf1 = *(const short8v*)(V1 + dt * 1024);
            __builtin_amdgcn_s_setprio(1);
            #pragma unroll
            for (int m = 0; m < 2; ++m) {
                o[m][dt] = __builtin_amdgcn_mfma_f32_16x16x32_bf16(
                    __builtin_bit_cast(short8v, afu[m][0]), vf0, o[m][dt], 0, 0, 0);
                o[m][dt] = __builtin_amdgcn_mfma_f32_16x16x32_bf16(
                    __builtin_bit_cast(short8v, afu[m][1]), vf1, o[m][dt], 0, 0, 0);
            }
            __builtin_amdgcn_s_setprio(0);
        }

        cur = (cur == 2) ? 0 : cur + 1;
    }
#undef STAGE

    // ---- epilogue: lacc rows (lg*4+r) match o rows exactly — no shuffles ----
    #pragma unroll
    for (int m = 0; m < 2; ++m) {
        #pragma unroll
        for (int dt = 0; dt < 4; ++dt) {
            #pragma unroll
            for (int r = 0; r < 4; ++r) {
                float v = o[m][dt][r] / lacc[m][r];
                int row = qb*256 + w*32 + m*16 + lg*4 + r;
                int col = h*HDIM + dt*16 + lq;
                attout[(size_t)(b*SEQ + row) * EMBED + col] = f2bf(v);
            }
        }
    }
}

// ---------------------------------------------------------------------------
extern "C" void kernel_launch(void* const* d_in, const int* in_sizes, int n_in,
                              void* d_out, int out_size, void* d_ws, size_t ws_size,
                              hipStream_t stream) {
    const float* x      = (const float*)d_in[0];
    const float* W_qkv  = (const float*)d_in[1];
    const float* b_qkv  = (const float*)d_in[2];
    const float* W_proj = (const float*)d_in[3];
    const float* b_proj = (const float*)d_in[4];
    float* out = (float*)d_out;

    const int M = BATCH * SEQ;   // 8192

    char* ws = (char*)d_ws;
    unsigned short* x_b    = (unsigned short*)(ws);                 // 16 MB
    unsigned short* wqkvT  = (unsigned short*)(ws + 16777216);      // 6 MB
    unsigned short* wprojT = (unsigned short*)(ws + 23068672);      // 2 MB
    unsigned short* qkv_b  = (unsigned short*)(ws + 25165824);      // 48 MB
    unsigned short* vt_b   = (unsigned short*)(ws + 75497472);      // 16 MB
    unsigned short* att_b  = (unsigned short*)(ws + 92274688);      // 16 MB

    cast_f32_bf16<<<dim3((M * EMBED) / 1024), 256, 0, stream>>>(x, x_b);
    transpose_cast<<<dim3(QKV_LD / 64, EMBED / 64), 256, 0, stream>>>(W_qkv, wqkvT, EMBED, QKV_LD);
    transpose_cast<<<dim3(EMBED / 64, EMBED / 64), 256, 0, stream>>>(W_proj, wprojT, EMBED, EMBED);

    // QKV: grid (8192/256)*(3072/128) = 32*24 = 768 blocks
    gemm_bf16<true, true><<<dim3(768), 512, 0, stream>>>(
        x_b, wqkvT, b_qkv, qkv_b, M, QKV_LD, EMBED);

    vt_kernel<<<dim3(SEQ / 64, BATCH * HEADS), 256, 0, stream>>>(qkv_b, vt_b);

    // attn: grid 512 (QBLK=256)
    attn_mfma<<<dim3(512), dim3(512), 0, stream>>>(qkv_b, vt_b, att_b);

    // proj: grid (8192/256)*(1024/128) = 32*8 = 256 blocks
    gemm_bf16<false, false><<<dim3(256), 512, 0, stream>>>(
        att_b, wprojT, b_proj, out, M, EMBED, EMBED);
}